// Round 12
// baseline (552.763 us; speedup 1.0000x reference)
//
#include <hip/hip_runtime.h>

#define B_TOK 32768
#define D_IN  256
#define H_LAT 8192
#define TOPK  32
#define MT    32          // rows per block (32 -> 35KB LDS -> 4 blocks/CU)
#define NT    128         // h-cols per chunk
#define NCH   (H_LAT / NT)
#define CAP   144         // candidate pool per row (thr=2.3sigma -> lambda~90)
#define DELTA 0.016f      // exact-rescore window; ~8 sigma of bf16-GEMM+pack err

typedef __attribute__((ext_vector_type(4))) float f32x4;
typedef __attribute__((ext_vector_type(8))) short bf16x8;

__device__ __forceinline__ unsigned short f2bf(float f) {   // RNE fp32->bf16
    unsigned u = __float_as_uint(f);
    return (unsigned short)((u + 0x7fffu + ((u >> 16) & 1u)) >> 16);
}
__device__ __forceinline__ float bf2f(unsigned short u) {
    return __uint_as_float((unsigned)u << 16);
}

// Kernel A: one WAVE per 16-col tile; coalesced swizzled W_enc->bf16 (+sumW^2),
// linear Wd->bf16 copy. (R11 version, unchanged.)
__global__ __launch_bounds__(256)
void conv_kernel(const float* __restrict__ W, unsigned short* __restrict__ Wbf,
                 float* __restrict__ s2w, const float* __restrict__ Wd,
                 unsigned short* __restrict__ Wdbf) {
    const int tid  = threadIdx.x;
    const int wave = tid >> 6, lane = tid & 63;
    const int l15 = lane & 15, quad = lane >> 4;
    const int ct16 = blockIdx.x * 4 + wave;             // 128 blocks x 4 waves = 512 tiles

    float acc = 0.0f;
    {
        const float* src = W + (size_t)(ct16 * 16 + l15) * D_IN + quad * 8;
        unsigned short* dst = Wbf + ((size_t)ct16 * 8) * 512 + lane * 8;
#pragma unroll
        for (int c8 = 0; c8 < 8; ++c8) {
            const float4 v0 = *(const float4*)(src + c8 * 32);
            const float4 v1 = *(const float4*)(src + c8 * 32 + 4);
            acc += v0.x * v0.x + v0.y * v0.y + v0.z * v0.z + v0.w * v0.w +
                   v1.x * v1.x + v1.y * v1.y + v1.z * v1.z + v1.w * v1.w;
            ushort4 p0, p1;
            p0.x = f2bf(v0.x); p0.y = f2bf(v0.y); p0.z = f2bf(v0.z); p0.w = f2bf(v0.w);
            p1.x = f2bf(v1.x); p1.y = f2bf(v1.y); p1.z = f2bf(v1.z); p1.w = f2bf(v1.w);
            *(ushort4*)(dst + c8 * 512)     = p0;       // coalesced 1KB/wave
            *(ushort4*)(dst + c8 * 512 + 4) = p1;
        }
    }
    {
        const int total4 = (H_LAT * D_IN) / 4;
        for (int i = blockIdx.x * blockDim.x + tid; i < total4; i += 128 * 256) {
            const float4 d = ((const float4*)Wd)[i];
            ushort4 od;
            od.x = f2bf(d.x); od.y = f2bf(d.y); od.z = f2bf(d.z); od.w = f2bf(d.w);
            ((ushort4*)Wdbf)[i] = od;
        }
    }
#pragma unroll
    for (int off = 32; off > 0; off >>= 1) acc += __shfl_down(acc, off, 64);
    if (lane == 0) atomicAdd(s2w, acc);
}

// Kernel B: R11 structure at MT=32: LDS 35KB -> 4 blocks/CU = 32 waves/CU
// (8/SIMD), doubling latency hiding for BOTH the GEMM phase (L2-B loads,
// LDS-A reads, collect chains) and the wave-local tail (rescore/shuffle/
// gather chains). B L2 traffic doubles (4GB, L2-resident) - below the wall.
__global__ __launch_bounds__(512, 4)
void sae_main(const float* __restrict__ x, const float* __restrict__ W_enc,
              const float* __restrict__ b_enc, const float* __restrict__ b_dec,
              float* __restrict__ out,
              const unsigned short* __restrict__ Wbf, const float* __restrict__ s2w,
              const unsigned short* __restrict__ Wdbf) {
    // smem: [0, 16384)     A_frag[16][512] ushort (UNION tail ext scratch 3KB)
    //       [16384, 34816) pool[32][144]
    __shared__ __align__(16) char smem[16384 + MT * CAP * 4];
    __shared__ int   cnt[MT];
    __shared__ float thr[MT];

    unsigned short* A = (unsigned short*)smem;
    auto pool = reinterpret_cast<unsigned (*)[CAP]>(smem + 16384);
    unsigned short* ext_i = (unsigned short*)smem;          // [8 waves][64] (1 KB)
    float*          ext_v = (float*)(smem + 1024);          // [8 waves][64] (2 KB)

    const int tid  = threadIdx.x;
    const int row0 = blockIdx.x * MT;
    const int wave = tid >> 6, lane = tid & 63;
    const int l15 = lane & 15, quad = lane >> 4;

    if (tid < MT) { cnt[tid] = 0; thr[tid] = 0.0f; }
    __syncthreads();

    // ---- Phase 0: stage (x - b_dec) -> bf16 LDS in FRAGMENT order ----
    // 16 threads/row, 16 k each. k = q*16 + 0..15 -> c8 = q>>1, j = (q&1)*2+jj.
    {
        const int r = tid >> 4, q = tid & 15;
        const float* xr = x + (size_t)(row0 + r) * D_IN + q * 16;
        const float* bd = b_dec + q * 16;
        unsigned short* dst = A + ((r >> 4) * 8 + (q >> 1)) * 512 + (r & 15) * 8
                                + (q & 1) * 256;
        float s2 = 0.0f;
#pragma unroll
        for (int jj = 0; jj < 2; ++jj) {
            const float4 a = ((const float4*)xr)[2 * jj];
            const float4 b = ((const float4*)xr)[2 * jj + 1];
            const float4 da = ((const float4*)bd)[2 * jj];
            const float4 db = ((const float4*)bd)[2 * jj + 1];
            float v[8] = {a.x - da.x, a.y - da.y, a.z - da.z, a.w - da.w,
                          b.x - db.x, b.y - db.y, b.z - db.z, b.w - db.w};
            ushort4 p0, p1;
            p0.x = f2bf(v[0]); p0.y = f2bf(v[1]); p0.z = f2bf(v[2]); p0.w = f2bf(v[3]);
            p1.x = f2bf(v[4]); p1.y = f2bf(v[5]); p1.z = f2bf(v[6]); p1.w = f2bf(v[7]);
#pragma unroll
            for (int e = 0; e < 8; ++e) s2 += v[e] * v[e];
            *(ushort4*)(dst + jj * 128)     = p0;
            *(ushort4*)(dst + jj * 128 + 4) = p1;
        }
        atomicAdd(&thr[r], s2);
    }
    __syncthreads();
    if (tid < MT) {
        const float s2wm = s2w[0] * (1.0f / ((float)H_LAT * (float)D_IN));
        thr[tid] = 2.3f * sqrtf(s2wm * thr[tid]);
    }
    __syncthreads();

    float thrv[2][4];
#pragma unroll
    for (int mt = 0; mt < 2; ++mt)
#pragma unroll
        for (int qi = 0; qi < 4; ++qi) thrv[mt][qi] = thr[mt * 16 + quad * 4 + qi];

    // ---- Phase 1: MFMA K-loop over 4-chunk groups; wave owns 16-col strip ----
    const unsigned short* bp = Wbf + (size_t)(wave * 8) * 512 + lane * 8;
    const unsigned short* ap = A + lane * 8;                // conflict-free A base
    const float* bep = b_enc + wave * 16 + l15;
    int col0 = wave * 16 + l15;

    int pos[2][4];
    auto collect = [&](const f32x4 (&ac)[2], int cbase) {
        const unsigned colk = (unsigned)(8191 - cbase);
#pragma unroll
        for (int mt = 0; mt < 2; ++mt)
#pragma unroll
            for (int qi = 0; qi < 4; ++qi) {
                pos[mt][qi] = -1;
                if (ac[mt][qi] > thrv[mt][qi])
                    pos[mt][qi] = atomicAdd(&cnt[mt * 16 + quad * 4 + qi], 1);
            }
#pragma unroll
        for (int mt = 0; mt < 2; ++mt)
#pragma unroll
            for (int qi = 0; qi < 4; ++qi) {
                if ((unsigned)pos[mt][qi] < CAP)
                    pool[mt * 16 + quad * 4 + qi][pos[mt][qi]] =
                        ((unsigned)f2bf(ac[mt][qi]) << 13) | colk;
            }
    };

    for (int g = 0; g < NCH; g += 4) {
        const float bv0 = bep[0],      bv1 = bep[NT];
        const float bv2 = bep[2 * NT], bv3 = bep[3 * NT];

        f32x4 acc0[2], acc1[2], acc2[2], acc3[2];
#pragma unroll
        for (int mt = 0; mt < 2; ++mt) {
            acc0[mt] = {bv0, bv0, bv0, bv0};                // C-in = bias
            acc1[mt] = {bv1, bv1, bv1, bv1};
            acc2[mt] = {bv2, bv2, bv2, bv2};
            acc3[mt] = {bv3, bv3, bv3, bv3};
        }

#pragma unroll
        for (int c8 = 0; c8 < 8; ++c8) {
            const bf16x8 a0 = *(const bf16x8*)(ap + (0 * 8 + c8) * 512);
            const bf16x8 a1 = *(const bf16x8*)(ap + (1 * 8 + c8) * 512);
            const bf16x8 w0 = *(const bf16x8*)(bp + c8 * 512);
            const bf16x8 w1 = *(const bf16x8*)(bp + 32768 + c8 * 512);
            const bf16x8 w2 = *(const bf16x8*)(bp + 65536 + c8 * 512);
            const bf16x8 w3 = *(const bf16x8*)(bp + 98304 + c8 * 512);
            acc0[0] = __builtin_amdgcn_mfma_f32_16x16x32_bf16(a0, w0, acc0[0], 0, 0, 0);
            acc0[1] = __builtin_amdgcn_mfma_f32_16x16x32_bf16(a1, w0, acc0[1], 0, 0, 0);
            acc1[0] = __builtin_amdgcn_mfma_f32_16x16x32_bf16(a0, w1, acc1[0], 0, 0, 0);
            acc1[1] = __builtin_amdgcn_mfma_f32_16x16x32_bf16(a1, w1, acc1[1], 0, 0, 0);
            acc2[0] = __builtin_amdgcn_mfma_f32_16x16x32_bf16(a0, w2, acc2[0], 0, 0, 0);
            acc2[1] = __builtin_amdgcn_mfma_f32_16x16x32_bf16(a1, w2, acc2[1], 0, 0, 0);
            acc3[0] = __builtin_amdgcn_mfma_f32_16x16x32_bf16(a0, w3, acc3[0], 0, 0, 0);
            acc3[1] = __builtin_amdgcn_mfma_f32_16x16x32_bf16(a1, w3, acc3[1], 0, 0, 0);
        }

        collect(acc0, col0);
        collect(acc1, col0 + NT);
        collect(acc2, col0 + 2 * NT);
        collect(acc3, col0 + 3 * NT);

        bp  += 4 * 32768;                                   // 4 chunks (8 ct16 each)
        bep += 4 * NT;
        col0 += 4 * NT;
    }
    __syncthreads();    // pools complete; A dead -> ext scratch overlays it.
                        // NO barriers below: each wave fully owns its 4 rows.

    unsigned short* ei = ext_i + wave * 64;                 // this wave's scratch
    float*          ev = ext_v + wave * 64;

    for (int rr = 0; rr < 4; ++rr) {
        const int r = wave * 4 + rr;                        // row within block
        const int n = min(cnt[r], CAP);

        // ---- rank-count on packed keys -> top-64 (idx + approx val) ----
        unsigned p[3]; int rk[3];
        const int S = (n <= 128) ? 2 : 3;                   // wave-uniform
#pragma unroll
        for (int e = 0; e < 3; ++e) {
            const int c = e * 64 + lane;
            p[e] = (c < n) ? pool[r][c] : (unsigned)(c + 1);  // unique tiny sentinels
            rk[e] = 0;
        }
        if (S == 2) {
            for (int s = 0; s < 64; ++s) {
                const int src = (lane + s) & 63;
                const unsigned q0 = (unsigned)__shfl((int)p[0], src, 64);
                const unsigned q1 = (unsigned)__shfl((int)p[1], src, 64);
                rk[0] += (q0 > p[0]) + (q1 > p[0]);
                rk[1] += (q0 > p[1]) + (q1 > p[1]);
            }
        } else {
            for (int s = 0; s < 64; ++s) {
                const int src = (lane + s) & 63;
#pragma unroll
                for (int e = 0; e < 3; ++e) {
                    const unsigned q = (unsigned)__shfl((int)p[e], src, 64);
#pragma unroll
                    for (int a = 0; a < 3; ++a) rk[a] += (q > p[a]);
                }
            }
        }
#pragma unroll
        for (int e = 0; e < 3; ++e) {
            if (e < S && rk[e] < 64) {
                if (p[e] >= 8192u) {                        // real entry
                    ei[rk[e]] = (unsigned short)(8191 - (p[e] & 0x1fffu));
                    ev[rk[e]] = __uint_as_float((p[e] >> 13) << 16);
                } else {                                    // filler: unique sentinel
                    ei[rk[e]] = (unsigned short)(0x2000 + rk[e]);
                    ev[rk[e]] = 0.0f;
                }
            }
        }
        // all 64 slots written by this wave; same-wave LDS ops are ordered

        // ---- exact serial-fmaf rescore of the boundary window (j = lane) ----
        const float v32 = ev[TOPK - 1];                     // approx 32nd value
        const float va  = ev[lane];
        const int   h   = ei[lane];
        float v = va;
        if (h < H_LAT && fabsf(va - v32) <= DELTA) {
            const float* xr  = x + (size_t)(row0 + r) * D_IN;
            const float* wr_ = W_enc + (size_t)h * D_IN;
            float s = 0.0f;
            for (int kk = 0; kk < D_IN / 4; ++kk) {         // serial fmaf == np oracle
                const float4 xv = ((const float4*)xr)[kk];
                const float4 dv = ((const float4*)b_dec)[kk];
                const float4 wv = ((const float4*)wr_)[kk];
                s = fmaf(xv.x - dv.x, wv.x, s);
                s = fmaf(xv.y - dv.y, wv.y, s);
                s = fmaf(xv.z - dv.z, wv.z, s);
                s = fmaf(xv.w - dv.w, wv.w, s);
            }
            v = fmaxf(s + b_enc[h], 0.0f);
        }

        // ---- final rank -> top-32 -> bf16 decoder ----
        int rank = 0;
        for (int s = 0; s < 64; ++s) {
            const int src = (lane + s) & 63;
            const float wv = __shfl(v, src, 64);
            const int   wh = __shfl(h, src, 64);
            rank += (wv > v) || (wv == v && wh < h);        // val desc, idx asc; keys unique
        }
        if (rank < TOPK) { ev[rank] = v; ei[rank] = (unsigned short)h; }

        const float4 bd4 = *(const float4*)&b_dec[lane * 4];
        float4 o = bd4;                                     // wave-in-order: writes visible below
#pragma unroll 8
        for (int k = 0; k < TOPK; ++k) {
            const float vv = ev[k];                         // LDS broadcast
            const int   hh = ei[k];
            if (hh < H_LAT) {                               // wave-uniform (guards sentinel)
                const ushort4 w = *(const ushort4*)&Wdbf[(size_t)hh * D_IN + lane * 4];
                o.x = fmaf(vv, bf2f(w.x), o.x); o.y = fmaf(vv, bf2f(w.y), o.y);
                o.z = fmaf(vv, bf2f(w.z), o.z); o.w = fmaf(vv, bf2f(w.w), o.w);
            }
        }
        *(float4*)&out[(size_t)(row0 + r) * D_IN + lane * 4] = o;
    }
}

extern "C" void kernel_launch(void* const* d_in, const int* in_sizes, int n_in,
                              void* d_out, int out_size, void* d_ws, size_t ws_size,
                              hipStream_t stream) {
    const float* x     = (const float*)d_in[0];
    const float* W_enc = (const float*)d_in[1];
    const float* b_enc = (const float*)d_in[2];
    const float* W_dec = (const float*)d_in[3];
    const float* b_dec = (const float*)d_in[4];
    float* out = (float*)d_out;

    const size_t wel = (size_t)H_LAT * D_IN;                    // 2M elements
    float* s2w = (float*)d_ws;                                  // 1 float @ offset 0
    unsigned short* Wbf  = (unsigned short*)((char*)d_ws + 256); // 4 MB bf16 W_enc (swizzled)
    unsigned short* Wdbf = Wbf + wel;                            // 4 MB bf16 W_dec (linear)

    hipMemsetAsync(d_ws, 0, 256, stream);                       // zero s2w (ws is poisoned)
    conv_kernel<<<dim3(128), dim3(256), 0, stream>>>(W_enc, Wbf, s2w, W_dec, Wdbf);
    sae_main<<<dim3(B_TOK / MT), dim3(512), 0, stream>>>(x, W_enc, b_enc, b_dec,
                                                         out, Wbf, s2w, Wdbf);
}

// Round 13
// 517.038 us; speedup vs baseline: 1.0691x; 1.0691x over previous
//
#include <hip/hip_runtime.h>

#define B_TOK 32768
#define D_IN  256
#define H_LAT 8192
#define TOPK  32
#define MT    64          // rows per block
#define NT    128         // h-cols per chunk
#define NCH   (H_LAT / NT)
#define CAP   144         // candidate pool per row (thr=2.3sigma -> lambda~90)
#define DELTA 0.016f      // exact-rescore window; ~8 sigma of bf16-GEMM+pack err

typedef __attribute__((ext_vector_type(4))) float f32x4;
typedef __attribute__((ext_vector_type(8))) short bf16x8;

__device__ __forceinline__ unsigned short f2bf(float f) {   // RNE fp32->bf16
    unsigned u = __float_as_uint(f);
    return (unsigned short)((u + 0x7fffu + ((u >> 16) & 1u)) >> 16);
}
__device__ __forceinline__ float bf2f(unsigned short u) {
    return __uint_as_float((unsigned)u << 16);
}

// Kernel A: 512 blocks (2 blocks/CU). Block = one 16-col tile; the 4 waves
// split the 8 c8-fragments (2 each). Coalesced swizzled W_enc->bf16 (+sumW^2);
// Wd->bf16 linear copy grid-strided over all 512 blocks.
__global__ __launch_bounds__(256)
void conv_kernel(const float* __restrict__ W, unsigned short* __restrict__ Wbf,
                 float* __restrict__ s2w, const float* __restrict__ Wd,
                 unsigned short* __restrict__ Wdbf) {
    const int tid  = threadIdx.x;
    const int wave = tid >> 6, lane = tid & 63;
    const int l15 = lane & 15, quad = lane >> 4;
    const int ct16 = blockIdx.x;                        // 512 tiles

    float acc = 0.0f;
    {
        const float* src = W + (size_t)(ct16 * 16 + l15) * D_IN + quad * 8;
        unsigned short* dst = Wbf + (size_t)ct16 * 4096 + lane * 8;
#pragma unroll
        for (int cc = 0; cc < 2; ++cc) {
            const int c8 = wave * 2 + cc;
            const float4 v0 = *(const float4*)(src + c8 * 32);
            const float4 v1 = *(const float4*)(src + c8 * 32 + 4);
            acc += v0.x * v0.x + v0.y * v0.y + v0.z * v0.z + v0.w * v0.w +
                   v1.x * v1.x + v1.y * v1.y + v1.z * v1.z + v1.w * v1.w;
            ushort4 p0, p1;
            p0.x = f2bf(v0.x); p0.y = f2bf(v0.y); p0.z = f2bf(v0.z); p0.w = f2bf(v0.w);
            p1.x = f2bf(v1.x); p1.y = f2bf(v1.y); p1.z = f2bf(v1.z); p1.w = f2bf(v1.w);
            *(ushort4*)(dst + c8 * 512)     = p0;       // coalesced
            *(ushort4*)(dst + c8 * 512 + 4) = p1;
        }
    }
    {
        const int total4 = (H_LAT * D_IN) / 4;
        for (int i = blockIdx.x * 256 + tid; i < total4; i += 512 * 256) {
            const float4 d = ((const float4*)Wd)[i];
            ushort4 od;
            od.x = f2bf(d.x); od.y = f2bf(d.y); od.z = f2bf(d.z); od.w = f2bf(d.w);
            ((ushort4*)Wdbf)[i] = od;
        }
    }
#pragma unroll
    for (int off = 32; off > 0; off >>= 1) acc += __shfl_down(acc, off, 64);
    if (lane == 0) atomicAdd(s2w, acc);
}

// One pipeline step: prefetch next c8's B fragments (NW*), read A, 8 MFMAs
// consuming the PREVIOUS step's B (CW*) -> B L2 latency hidden by one step.
#define GSTEP(CW0, CW1, NW0, NW1, C8, NBASE, NC8)                              \
    {                                                                          \
        NW0 = *(const bf16x8*)((NBASE) + (NC8) * 512);                         \
        NW1 = *(const bf16x8*)((NBASE) + 32768 + (NC8) * 512);                 \
        const bf16x8 a0 = *(const bf16x8*)(ap + (0 * 8 + (C8)) * 512);         \
        const bf16x8 a1 = *(const bf16x8*)(ap + (1 * 8 + (C8)) * 512);         \
        const bf16x8 a2 = *(const bf16x8*)(ap + (2 * 8 + (C8)) * 512);         \
        const bf16x8 a3 = *(const bf16x8*)(ap + (3 * 8 + (C8)) * 512);         \
        acc0[0] = __builtin_amdgcn_mfma_f32_16x16x32_bf16(a0, CW0, acc0[0], 0, 0, 0); \
        acc0[1] = __builtin_amdgcn_mfma_f32_16x16x32_bf16(a1, CW0, acc0[1], 0, 0, 0); \
        acc0[2] = __builtin_amdgcn_mfma_f32_16x16x32_bf16(a2, CW0, acc0[2], 0, 0, 0); \
        acc0[3] = __builtin_amdgcn_mfma_f32_16x16x32_bf16(a3, CW0, acc0[3], 0, 0, 0); \
        acc1[0] = __builtin_amdgcn_mfma_f32_16x16x32_bf16(a0, CW1, acc1[0], 0, 0, 0); \
        acc1[1] = __builtin_amdgcn_mfma_f32_16x16x32_bf16(a1, CW1, acc1[1], 0, 0, 0); \
        acc1[2] = __builtin_amdgcn_mfma_f32_16x16x32_bf16(a2, CW1, acc1[2], 0, 0, 0); \
        acc1[3] = __builtin_amdgcn_mfma_f32_16x16x32_bf16(a3, CW1, acc1[3], 0, 0, 0); \
    }

// Kernel B: R11 structure (MT=64, wave-local tail) with:
//  - 2-chunk groups + explicit ping-pong B prefetch (wa/wb): MFMAs consume
//    fragments loaded one step earlier -> L2 latency hidden (acc 32 regs,
//    B dbuf 16 regs: fits without spill, unlike R3's 128-reg attempt)
//  - rescore kk-loop unrolled 16x: 48 loads in flight instead of a 64-deep
//    serial load->fmaf latency chain (exactness unchanged: same fmaf order)
__global__ __launch_bounds__(512, 4)
void sae_main(const float* __restrict__ x, const float* __restrict__ W_enc,
              const float* __restrict__ b_enc, const float* __restrict__ b_dec,
              float* __restrict__ out,
              const unsigned short* __restrict__ Wbf, const float* __restrict__ s2w,
              const unsigned short* __restrict__ Wdbf) {
    // smem: [0, 32768)     A_frag[32][512] ushort (UNION tail ext scratch 3KB)
    //       [32768, 69632) pool[64][144]
    __shared__ __align__(16) char smem[32768 + MT * CAP * 4];
    __shared__ int   cnt[MT];
    __shared__ float thr[MT];

    unsigned short* A = (unsigned short*)smem;
    auto pool = reinterpret_cast<unsigned (*)[CAP]>(smem + 32768);
    unsigned short* ext_i = (unsigned short*)smem;          // [8 waves][64] (1 KB)
    float*          ext_v = (float*)(smem + 1024);          // [8 waves][64] (2 KB)

    const int tid  = threadIdx.x;
    const int row0 = blockIdx.x * MT;
    const int wave = tid >> 6, lane = tid & 63;
    const int l15 = lane & 15, quad = lane >> 4;

    if (tid < MT) { cnt[tid] = 0; thr[tid] = 0.0f; }
    __syncthreads();

    // ---- Phase 0: stage (x - b_dec) -> bf16 LDS in FRAGMENT order ----
    {
        const int r = tid >> 3, q = tid & 7;                // 8 threads/row, 32 k each
        const float* xr = x + (size_t)(row0 + r) * D_IN + q * 32;
        const float* bd = b_dec + q * 32;
        unsigned short* dst = A + ((r >> 4) * 8 + q) * 512 + (r & 15) * 8;
        float s2 = 0.0f;
#pragma unroll
        for (int j = 0; j < 4; ++j) {                       // j = quad-of-k
            const float4 a = ((const float4*)xr)[2 * j];
            const float4 b = ((const float4*)xr)[2 * j + 1];
            const float4 da = ((const float4*)bd)[2 * j];
            const float4 db = ((const float4*)bd)[2 * j + 1];
            float v[8] = {a.x - da.x, a.y - da.y, a.z - da.z, a.w - da.w,
                          b.x - db.x, b.y - db.y, b.z - db.z, b.w - db.w};
            ushort4 p0, p1;
            p0.x = f2bf(v[0]); p0.y = f2bf(v[1]); p0.z = f2bf(v[2]); p0.w = f2bf(v[3]);
            p1.x = f2bf(v[4]); p1.y = f2bf(v[5]); p1.z = f2bf(v[6]); p1.w = f2bf(v[7]);
#pragma unroll
            for (int e = 0; e < 8; ++e) s2 += v[e] * v[e];
            *(ushort4*)(dst + j * 128)     = p0;
            *(ushort4*)(dst + j * 128 + 4) = p1;
        }
        atomicAdd(&thr[r], s2);
    }
    __syncthreads();
    if (tid < MT) {
        const float s2wm = s2w[0] * (1.0f / ((float)H_LAT * (float)D_IN));
        thr[tid] = 2.3f * sqrtf(s2wm * thr[tid]);
    }
    __syncthreads();

    float thrv[4][4];
#pragma unroll
    for (int mt = 0; mt < 4; ++mt)
#pragma unroll
        for (int qi = 0; qi < 4; ++qi) thrv[mt][qi] = thr[mt * 16 + quad * 4 + qi];

    // ---- Phase 1: MFMA K-loop, 2-chunk groups, ping-pong B prefetch ----
    const unsigned short* bp = Wbf + (size_t)(wave * 8) * 512 + lane * 8;
    const unsigned short* ap = A + lane * 8;                // conflict-free A base
    const float* bep = b_enc + wave * 16 + l15;
    int col0 = wave * 16 + l15;

    int pos[4][4];
    auto collect = [&](const f32x4 (&ac)[4], int cbase) {
        const unsigned colk = (unsigned)(8191 - cbase);
#pragma unroll
        for (int mt = 0; mt < 4; ++mt)
#pragma unroll
            for (int qi = 0; qi < 4; ++qi) {
                pos[mt][qi] = -1;
                if (ac[mt][qi] > thrv[mt][qi])
                    pos[mt][qi] = atomicAdd(&cnt[mt * 16 + quad * 4 + qi], 1);
            }
#pragma unroll
        for (int mt = 0; mt < 4; ++mt)
#pragma unroll
            for (int qi = 0; qi < 4; ++qi) {
                if ((unsigned)pos[mt][qi] < CAP)
                    pool[mt * 16 + quad * 4 + qi][pos[mt][qi]] =
                        ((unsigned)f2bf(ac[mt][qi]) << 13) | colk;
            }
    };

    bf16x8 wa0, wa1, wb0, wb1;
    wa0 = *(const bf16x8*)(bp);                             // preload group 0, c8=0
    wa1 = *(const bf16x8*)(bp + 32768);

    for (int g = 0; g < NCH; g += 2) {
        const float bv0 = bep[0], bv1 = bep[NT];

        f32x4 acc0[4], acc1[4];
#pragma unroll
        for (int mt = 0; mt < 4; ++mt) {
            acc0[mt] = {bv0, bv0, bv0, bv0};                // C-in = bias
            acc1[mt] = {bv1, bv1, bv1, bv1};
        }

        GSTEP(wa0, wa1, wb0, wb1, 0, bp, 1);
        GSTEP(wb0, wb1, wa0, wa1, 1, bp, 2);
        GSTEP(wa0, wa1, wb0, wb1, 2, bp, 3);
        GSTEP(wb0, wb1, wa0, wa1, 3, bp, 4);
        GSTEP(wa0, wa1, wb0, wb1, 4, bp, 5);
        GSTEP(wb0, wb1, wa0, wa1, 5, bp, 6);
        GSTEP(wa0, wa1, wb0, wb1, 6, bp, 7);
        GSTEP(wb0, wb1, wa0, wa1, 7, bp + 65536, 0);        // prefetch next group
        // (final group prefetches 16B past Wbf -> lands in Wdbf region: safe, unused)

        collect(acc0, col0);
        collect(acc1, col0 + NT);

        bp  += 65536;                                       // 2 chunks (8 ct16 each)
        bep += 2 * NT;
        col0 += 2 * NT;
    }
    __syncthreads();    // pools complete; A dead -> ext scratch overlays it.
                        // NO barriers below: each wave fully owns its 8 rows.

    unsigned short* ei = ext_i + wave * 64;                 // this wave's scratch
    float*          ev = ext_v + wave * 64;

    for (int rr = 0; rr < 8; ++rr) {
        const int r = wave * 8 + rr;                        // row within block
        const int n = min(cnt[r], CAP);

        // ---- rank-count on packed keys -> top-64 (idx + approx val) ----
        unsigned p[3]; int rk[3];
        const int S = (n <= 128) ? 2 : 3;                   // wave-uniform
#pragma unroll
        for (int e = 0; e < 3; ++e) {
            const int c = e * 64 + lane;
            p[e] = (c < n) ? pool[r][c] : (unsigned)(c + 1);  // unique tiny sentinels
            rk[e] = 0;
        }
        if (S == 2) {
            for (int s = 0; s < 64; ++s) {
                const int src = (lane + s) & 63;
                const unsigned q0 = (unsigned)__shfl((int)p[0], src, 64);
                const unsigned q1 = (unsigned)__shfl((int)p[1], src, 64);
                rk[0] += (q0 > p[0]) + (q1 > p[0]);
                rk[1] += (q0 > p[1]) + (q1 > p[1]);
            }
        } else {
            for (int s = 0; s < 64; ++s) {
                const int src = (lane + s) & 63;
#pragma unroll
                for (int e = 0; e < 3; ++e) {
                    const unsigned q = (unsigned)__shfl((int)p[e], src, 64);
#pragma unroll
                    for (int a = 0; a < 3; ++a) rk[a] += (q > p[a]);
                }
            }
        }
#pragma unroll
        for (int e = 0; e < 3; ++e) {
            if (e < S && rk[e] < 64) {
                if (p[e] >= 8192u) {                        // real entry
                    ei[rk[e]] = (unsigned short)(8191 - (p[e] & 0x1fffu));
                    ev[rk[e]] = __uint_as_float((p[e] >> 13) << 16);
                } else {                                    // filler: unique sentinel
                    ei[rk[e]] = (unsigned short)(0x2000 + rk[e]);
                    ev[rk[e]] = 0.0f;
                }
            }
        }
        // all 64 slots written by this wave; same-wave LDS ops are ordered

        // ---- exact serial-fmaf rescore of the boundary window (j = lane) ----
        const float v32 = ev[TOPK - 1];                     // approx 32nd value
        const float va  = ev[lane];
        const int   h   = ei[lane];
        float v = va;
        if (h < H_LAT && fabsf(va - v32) <= DELTA) {
            const float* xr  = x + (size_t)(row0 + r) * D_IN;
            const float* wr_ = W_enc + (size_t)h * D_IN;
            float s = 0.0f;
#pragma unroll 16
            for (int kk = 0; kk < D_IN / 4; ++kk) {         // serial fmaf == np oracle
                const float4 xv = ((const float4*)xr)[kk];
                const float4 dv = ((const float4*)b_dec)[kk];
                const float4 wv = ((const float4*)wr_)[kk];
                s = fmaf(xv.x - dv.x, wv.x, s);
                s = fmaf(xv.y - dv.y, wv.y, s);
                s = fmaf(xv.z - dv.z, wv.z, s);
                s = fmaf(xv.w - dv.w, wv.w, s);
            }
            v = fmaxf(s + b_enc[h], 0.0f);
        }

        // ---- final rank -> top-32 -> bf16 decoder ----
        int rank = 0;
        for (int s = 0; s < 64; ++s) {
            const int src = (lane + s) & 63;
            const float wv = __shfl(v, src, 64);
            const int   wh = __shfl(h, src, 64);
            rank += (wv > v) || (wv == v && wh < h);        // val desc, idx asc; keys unique
        }
        if (rank < TOPK) { ev[rank] = v; ei[rank] = (unsigned short)h; }

        const float4 bd4 = *(const float4*)&b_dec[lane * 4];
        float4 o = bd4;                                     // wave-in-order: writes visible below
#pragma unroll 8
        for (int k = 0; k < TOPK; ++k) {
            const float vv = ev[k];                         // LDS broadcast
            const int   hh = ei[k];
            if (hh < H_LAT) {                               // wave-uniform (guards sentinel)
                const ushort4 w = *(const ushort4*)&Wdbf[(size_t)hh * D_IN + lane * 4];
                o.x = fmaf(vv, bf2f(w.x), o.x); o.y = fmaf(vv, bf2f(w.y), o.y);
                o.z = fmaf(vv, bf2f(w.z), o.z); o.w = fmaf(vv, bf2f(w.w), o.w);
            }
        }
        *(float4*)&out[(size_t)(row0 + r) * D_IN + lane * 4] = o;
    }
}

extern "C" void kernel_launch(void* const* d_in, const int* in_sizes, int n_in,
                              void* d_out, int out_size, void* d_ws, size_t ws_size,
                              hipStream_t stream) {
    const float* x     = (const float*)d_in[0];
    const float* W_enc = (const float*)d_in[1];
    const float* b_enc = (const float*)d_in[2];
    const float* W_dec = (const float*)d_in[3];
    const float* b_dec = (const float*)d_in[4];
    float* out = (float*)d_out;

    const size_t wel = (size_t)H_LAT * D_IN;                    // 2M elements
    float* s2w = (float*)d_ws;                                  // 1 float @ offset 0
    unsigned short* Wbf  = (unsigned short*)((char*)d_ws + 256); // 4 MB bf16 W_enc (swizzled)
    unsigned short* Wdbf = Wbf + wel;                            // 4 MB bf16 W_dec (linear)

    hipMemsetAsync(d_ws, 0, 256, stream);                       // zero s2w (ws is poisoned)
    conv_kernel<<<dim3(512), dim3(256), 0, stream>>>(W_enc, Wbf, s2w, W_dec, Wdbf);
    sae_main<<<dim3(B_TOK / MT), dim3(512), 0, stream>>>(x, W_enc, b_enc, b_dec,
                                                         out, Wbf, s2w, Wdbf);
}

// Round 14
// 515.739 us; speedup vs baseline: 1.0718x; 1.0025x over previous
//
#include <hip/hip_runtime.h>

#define B_TOK 32768
#define D_IN  256
#define H_LAT 8192
#define TOPK  32
#define MT    64          // rows per block
#define NT    128         // h-cols per chunk
#define NCH   (H_LAT / NT)
#define CAP   144         // candidate pool per row (thr=2.3sigma -> lambda~90)
#define DELTA 0.016f      // exact-rescore window; ~8 sigma of bf16-GEMM+pack err

typedef __attribute__((ext_vector_type(4))) float f32x4;
typedef __attribute__((ext_vector_type(8))) short bf16x8;

__device__ __forceinline__ unsigned short f2bf(float f) {   // RNE fp32->bf16
    unsigned u = __float_as_uint(f);
    return (unsigned short)((u + 0x7fffu + ((u >> 16) & 1u)) >> 16);
}
__device__ __forceinline__ float bf2f(unsigned short u) {
    return __uint_as_float((unsigned)u << 16);
}

// Kernel A: 512 blocks (2 blocks/CU). Block = one 16-col tile; the 4 waves
// split the 8 c8-fragments (2 each). Coalesced swizzled W_enc->bf16 (+sumW^2);
// Wd->bf16 linear copy grid-strided over all 512 blocks. (R13, unchanged.)
__global__ __launch_bounds__(256)
void conv_kernel(const float* __restrict__ W, unsigned short* __restrict__ Wbf,
                 float* __restrict__ s2w, const float* __restrict__ Wd,
                 unsigned short* __restrict__ Wdbf) {
    const int tid  = threadIdx.x;
    const int wave = tid >> 6, lane = tid & 63;
    const int l15 = lane & 15, quad = lane >> 4;
    const int ct16 = blockIdx.x;                        // 512 tiles

    float acc = 0.0f;
    {
        const float* src = W + (size_t)(ct16 * 16 + l15) * D_IN + quad * 8;
        unsigned short* dst = Wbf + (size_t)ct16 * 4096 + lane * 8;
#pragma unroll
        for (int cc = 0; cc < 2; ++cc) {
            const int c8 = wave * 2 + cc;
            const float4 v0 = *(const float4*)(src + c8 * 32);
            const float4 v1 = *(const float4*)(src + c8 * 32 + 4);
            acc += v0.x * v0.x + v0.y * v0.y + v0.z * v0.z + v0.w * v0.w +
                   v1.x * v1.x + v1.y * v1.y + v1.z * v1.z + v1.w * v1.w;
            ushort4 p0, p1;
            p0.x = f2bf(v0.x); p0.y = f2bf(v0.y); p0.z = f2bf(v0.z); p0.w = f2bf(v0.w);
            p1.x = f2bf(v1.x); p1.y = f2bf(v1.y); p1.z = f2bf(v1.z); p1.w = f2bf(v1.w);
            *(ushort4*)(dst + c8 * 512)     = p0;       // coalesced
            *(ushort4*)(dst + c8 * 512 + 4) = p1;
        }
    }
    {
        const int total4 = (H_LAT * D_IN) / 4;
        for (int i = blockIdx.x * 256 + tid; i < total4; i += 512 * 256) {
            const float4 d = ((const float4*)Wd)[i];
            ushort4 od;
            od.x = f2bf(d.x); od.y = f2bf(d.y); od.z = f2bf(d.z); od.w = f2bf(d.w);
            ((ushort4*)Wdbf)[i] = od;
        }
    }
#pragma unroll
    for (int off = 32; off > 0; off >>= 1) acc += __shfl_down(acc, off, 64);
    if (lane == 0) atomicAdd(s2w, acc);
}

// One pipeline step: prefetch next c8's B fragments (global) AND next c8's A
// fragments (LDS) while the 8 MFMAs consume the PREVIOUS step's registers.
// Both the ~250cy L2 latency and the ~120cy LDS latency are hidden one step
// ahead. A depends only on c8 (reused across groups) so NAC8=(c8+1)&7 is
// always valid, including the wrap into the next group.
#define GSTEP(CW0, CW1, NW0, NW1, CA, NA, NBASE, NC8, NAC8)                    \
    {                                                                          \
        NW0 = *(const bf16x8*)((NBASE) + (NC8) * 512);                         \
        NW1 = *(const bf16x8*)((NBASE) + 32768 + (NC8) * 512);                 \
        NA[0] = *(const bf16x8*)(ap + (0 * 8 + (NAC8)) * 512);                 \
        NA[1] = *(const bf16x8*)(ap + (1 * 8 + (NAC8)) * 512);                 \
        NA[2] = *(const bf16x8*)(ap + (2 * 8 + (NAC8)) * 512);                 \
        NA[3] = *(const bf16x8*)(ap + (3 * 8 + (NAC8)) * 512);                 \
        acc0[0] = __builtin_amdgcn_mfma_f32_16x16x32_bf16(CA[0], CW0, acc0[0], 0, 0, 0); \
        acc0[1] = __builtin_amdgcn_mfma_f32_16x16x32_bf16(CA[1], CW0, acc0[1], 0, 0, 0); \
        acc0[2] = __builtin_amdgcn_mfma_f32_16x16x32_bf16(CA[2], CW0, acc0[2], 0, 0, 0); \
        acc0[3] = __builtin_amdgcn_mfma_f32_16x16x32_bf16(CA[3], CW0, acc0[3], 0, 0, 0); \
        acc1[0] = __builtin_amdgcn_mfma_f32_16x16x32_bf16(CA[0], CW1, acc1[0], 0, 0, 0); \
        acc1[1] = __builtin_amdgcn_mfma_f32_16x16x32_bf16(CA[1], CW1, acc1[1], 0, 0, 0); \
        acc1[2] = __builtin_amdgcn_mfma_f32_16x16x32_bf16(CA[2], CW1, acc1[2], 0, 0, 0); \
        acc1[3] = __builtin_amdgcn_mfma_f32_16x16x32_bf16(CA[3], CW1, acc1[3], 0, 0, 0); \
    }

// Kernel B: R13 structure (MT=64, 2-chunk groups, B ping-pong, wave-local
// tail, rescore unroll 16) + A-LDS ping-pong: the symmetric fix on the LDS
// side of what R13's B ping-pong did on the global side.
__global__ __launch_bounds__(512, 4)
void sae_main(const float* __restrict__ x, const float* __restrict__ W_enc,
              const float* __restrict__ b_enc, const float* __restrict__ b_dec,
              float* __restrict__ out,
              const unsigned short* __restrict__ Wbf, const float* __restrict__ s2w,
              const unsigned short* __restrict__ Wdbf) {
    // smem: [0, 32768)     A_frag[32][512] ushort (UNION tail ext scratch 3KB)
    //       [32768, 69632) pool[64][144]
    __shared__ __align__(16) char smem[32768 + MT * CAP * 4];
    __shared__ int   cnt[MT];
    __shared__ float thr[MT];

    unsigned short* A = (unsigned short*)smem;
    auto pool = reinterpret_cast<unsigned (*)[CAP]>(smem + 32768);
    unsigned short* ext_i = (unsigned short*)smem;          // [8 waves][64] (1 KB)
    float*          ext_v = (float*)(smem + 1024);          // [8 waves][64] (2 KB)

    const int tid  = threadIdx.x;
    const int row0 = blockIdx.x * MT;
    const int wave = tid >> 6, lane = tid & 63;
    const int l15 = lane & 15, quad = lane >> 4;

    if (tid < MT) { cnt[tid] = 0; thr[tid] = 0.0f; }
    __syncthreads();

    // ---- Phase 0: stage (x - b_dec) -> bf16 LDS in FRAGMENT order ----
    {
        const int r = tid >> 3, q = tid & 7;                // 8 threads/row, 32 k each
        const float* xr = x + (size_t)(row0 + r) * D_IN + q * 32;
        const float* bd = b_dec + q * 32;
        unsigned short* dst = A + ((r >> 4) * 8 + q) * 512 + (r & 15) * 8;
        float s2 = 0.0f;
#pragma unroll
        for (int j = 0; j < 4; ++j) {                       // j = quad-of-k
            const float4 a = ((const float4*)xr)[2 * j];
            const float4 b = ((const float4*)xr)[2 * j + 1];
            const float4 da = ((const float4*)bd)[2 * j];
            const float4 db = ((const float4*)bd)[2 * j + 1];
            float v[8] = {a.x - da.x, a.y - da.y, a.z - da.z, a.w - da.w,
                          b.x - db.x, b.y - db.y, b.z - db.z, b.w - db.w};
            ushort4 p0, p1;
            p0.x = f2bf(v[0]); p0.y = f2bf(v[1]); p0.z = f2bf(v[2]); p0.w = f2bf(v[3]);
            p1.x = f2bf(v[4]); p1.y = f2bf(v[5]); p1.z = f2bf(v[6]); p1.w = f2bf(v[7]);
#pragma unroll
            for (int e = 0; e < 8; ++e) s2 += v[e] * v[e];
            *(ushort4*)(dst + j * 128)     = p0;
            *(ushort4*)(dst + j * 128 + 4) = p1;
        }
        atomicAdd(&thr[r], s2);
    }
    __syncthreads();
    if (tid < MT) {
        const float s2wm = s2w[0] * (1.0f / ((float)H_LAT * (float)D_IN));
        thr[tid] = 2.3f * sqrtf(s2wm * thr[tid]);
    }
    __syncthreads();

    float thrv[4][4];
#pragma unroll
    for (int mt = 0; mt < 4; ++mt)
#pragma unroll
        for (int qi = 0; qi < 4; ++qi) thrv[mt][qi] = thr[mt * 16 + quad * 4 + qi];

    // ---- Phase 1: MFMA K-loop, 2-chunk groups, A+B ping-pong prefetch ----
    const unsigned short* bp = Wbf + (size_t)(wave * 8) * 512 + lane * 8;
    const unsigned short* ap = A + lane * 8;                // conflict-free A base
    const float* bep = b_enc + wave * 16 + l15;
    int col0 = wave * 16 + l15;

    int pos[4][4];
    auto collect = [&](const f32x4 (&ac)[4], int cbase) {
        const unsigned colk = (unsigned)(8191 - cbase);
#pragma unroll
        for (int mt = 0; mt < 4; ++mt)
#pragma unroll
            for (int qi = 0; qi < 4; ++qi) {
                pos[mt][qi] = -1;
                if (ac[mt][qi] > thrv[mt][qi])
                    pos[mt][qi] = atomicAdd(&cnt[mt * 16 + quad * 4 + qi], 1);
            }
#pragma unroll
        for (int mt = 0; mt < 4; ++mt)
#pragma unroll
            for (int qi = 0; qi < 4; ++qi) {
                if ((unsigned)pos[mt][qi] < CAP)
                    pool[mt * 16 + quad * 4 + qi][pos[mt][qi]] =
                        ((unsigned)f2bf(ac[mt][qi]) << 13) | colk;
            }
    };

    bf16x8 wa0, wa1, wb0, wb1;
    bf16x8 aA[4], aB[4];
    wa0 = *(const bf16x8*)(bp);                             // preload group 0, c8=0
    wa1 = *(const bf16x8*)(bp + 32768);
    aA[0] = *(const bf16x8*)(ap + 0 * 8 * 512);
    aA[1] = *(const bf16x8*)(ap + 1 * 8 * 512);
    aA[2] = *(const bf16x8*)(ap + 2 * 8 * 512);
    aA[3] = *(const bf16x8*)(ap + 3 * 8 * 512);

    for (int g = 0; g < NCH; g += 2) {
        const float bv0 = bep[0], bv1 = bep[NT];

        f32x4 acc0[4], acc1[4];
#pragma unroll
        for (int mt = 0; mt < 4; ++mt) {
            acc0[mt] = {bv0, bv0, bv0, bv0};                // C-in = bias
            acc1[mt] = {bv1, bv1, bv1, bv1};
        }

        GSTEP(wa0, wa1, wb0, wb1, aA, aB, bp, 1, 1);
        GSTEP(wb0, wb1, wa0, wa1, aB, aA, bp, 2, 2);
        GSTEP(wa0, wa1, wb0, wb1, aA, aB, bp, 3, 3);
        GSTEP(wb0, wb1, wa0, wa1, aB, aA, bp, 4, 4);
        GSTEP(wa0, wa1, wb0, wb1, aA, aB, bp, 5, 5);
        GSTEP(wb0, wb1, wa0, wa1, aB, aA, bp, 6, 6);
        GSTEP(wa0, wa1, wb0, wb1, aA, aB, bp, 7, 7);
        GSTEP(wb0, wb1, wa0, wa1, aB, aA, bp + 65536, 0, 0);  // prefetch next group
        // (final group prefetches 16B past Wbf -> lands in Wdbf region: safe, unused)

        collect(acc0, col0);
        collect(acc1, col0 + NT);

        bp  += 65536;                                       // 2 chunks (8 ct16 each)
        bep += 2 * NT;
        col0 += 2 * NT;
    }
    __syncthreads();    // pools complete; A dead -> ext scratch overlays it.
                        // NO barriers below: each wave fully owns its 8 rows.

    unsigned short* ei = ext_i + wave * 64;                 // this wave's scratch
    float*          ev = ext_v + wave * 64;

    for (int rr = 0; rr < 8; ++rr) {
        const int r = wave * 8 + rr;                        // row within block
        const int n = min(cnt[r], CAP);

        // ---- rank-count on packed keys -> top-64 (idx + approx val) ----
        unsigned p[3]; int rk[3];
        const int S = (n <= 128) ? 2 : 3;                   // wave-uniform
#pragma unroll
        for (int e = 0; e < 3; ++e) {
            const int c = e * 64 + lane;
            p[e] = (c < n) ? pool[r][c] : (unsigned)(c + 1);  // unique tiny sentinels
            rk[e] = 0;
        }
        if (S == 2) {
            for (int s = 0; s < 64; ++s) {
                const int src = (lane + s) & 63;
                const unsigned q0 = (unsigned)__shfl((int)p[0], src, 64);
                const unsigned q1 = (unsigned)__shfl((int)p[1], src, 64);
                rk[0] += (q0 > p[0]) + (q1 > p[0]);
                rk[1] += (q0 > p[1]) + (q1 > p[1]);
            }
        } else {
            for (int s = 0; s < 64; ++s) {
                const int src = (lane + s) & 63;
#pragma unroll
                for (int e = 0; e < 3; ++e) {
                    const unsigned q = (unsigned)__shfl((int)p[e], src, 64);
#pragma unroll
                    for (int a = 0; a < 3; ++a) rk[a] += (q > p[a]);
                }
            }
        }
#pragma unroll
        for (int e = 0; e < 3; ++e) {
            if (e < S && rk[e] < 64) {
                if (p[e] >= 8192u) {                        // real entry
                    ei[rk[e]] = (unsigned short)(8191 - (p[e] & 0x1fffu));
                    ev[rk[e]] = __uint_as_float((p[e] >> 13) << 16);
                } else {                                    // filler: unique sentinel
                    ei[rk[e]] = (unsigned short)(0x2000 + rk[e]);
                    ev[rk[e]] = 0.0f;
                }
            }
        }
        // all 64 slots written by this wave; same-wave LDS ops are ordered

        // ---- exact serial-fmaf rescore of the boundary window (j = lane) ----
        const float v32 = ev[TOPK - 1];                     // approx 32nd value
        const float va  = ev[lane];
        const int   h   = ei[lane];
        float v = va;
        if (h < H_LAT && fabsf(va - v32) <= DELTA) {
            const float* xr  = x + (size_t)(row0 + r) * D_IN;
            const float* wr_ = W_enc + (size_t)h * D_IN;
            float s = 0.0f;
#pragma unroll 16
            for (int kk = 0; kk < D_IN / 4; ++kk) {         // serial fmaf == np oracle
                const float4 xv = ((const float4*)xr)[kk];
                const float4 dv = ((const float4*)b_dec)[kk];
                const float4 wv = ((const float4*)wr_)[kk];
                s = fmaf(xv.x - dv.x, wv.x, s);
                s = fmaf(xv.y - dv.y, wv.y, s);
                s = fmaf(xv.z - dv.z, wv.z, s);
                s = fmaf(xv.w - dv.w, wv.w, s);
            }
            v = fmaxf(s + b_enc[h], 0.0f);
        }

        // ---- final rank -> top-32 -> bf16 decoder ----
        int rank = 0;
        for (int s = 0; s < 64; ++s) {
            const int src = (lane + s) & 63;
            const float wv = __shfl(v, src, 64);
            const int   wh = __shfl(h, src, 64);
            rank += (wv > v) || (wv == v && wh < h);        // val desc, idx asc; keys unique
        }
        if (rank < TOPK) { ev[rank] = v; ei[rank] = (unsigned short)h; }

        const float4 bd4 = *(const float4*)&b_dec[lane * 4];
        float4 o = bd4;                                     // wave-in-order: writes visible below
#pragma unroll 8
        for (int k = 0; k < TOPK; ++k) {
            const float vv = ev[k];                         // LDS broadcast
            const int   hh = ei[k];
            if (hh < H_LAT) {                               // wave-uniform (guards sentinel)
                const ushort4 w = *(const ushort4*)&Wdbf[(size_t)hh * D_IN + lane * 4];
                o.x = fmaf(vv, bf2f(w.x), o.x); o.y = fmaf(vv, bf2f(w.y), o.y);
                o.z = fmaf(vv, bf2f(w.z), o.z); o.w = fmaf(vv, bf2f(w.w), o.w);
            }
        }
        *(float4*)&out[(size_t)(row0 + r) * D_IN + lane * 4] = o;
    }
}

extern "C" void kernel_launch(void* const* d_in, const int* in_sizes, int n_in,
                              void* d_out, int out_size, void* d_ws, size_t ws_size,
                              hipStream_t stream) {
    const float* x     = (const float*)d_in[0];
    const float* W_enc = (const float*)d_in[1];
    const float* b_enc = (const float*)d_in[2];
    const float* W_dec = (const float*)d_in[3];
    const float* b_dec = (const float*)d_in[4];
    float* out = (float*)d_out;

    const size_t wel = (size_t)H_LAT * D_IN;                    // 2M elements
    float* s2w = (float*)d_ws;                                  // 1 float @ offset 0
    unsigned short* Wbf  = (unsigned short*)((char*)d_ws + 256); // 4 MB bf16 W_enc (swizzled)
    unsigned short* Wdbf = Wbf + wel;                            // 4 MB bf16 W_dec (linear)

    hipMemsetAsync(d_ws, 0, 256, stream);                       // zero s2w (ws is poisoned)
    conv_kernel<<<dim3(512), dim3(256), 0, stream>>>(W_enc, Wbf, s2w, W_dec, Wdbf);
    sae_main<<<dim3(B_TOK / MT), dim3(512), 0, stream>>>(x, W_enc, b_enc, b_dec,
                                                         out, Wbf, s2w, Wdbf);
}

// Round 15
// 510.520 us; speedup vs baseline: 1.0827x; 1.0102x over previous
//
#include <hip/hip_runtime.h>

#define B_TOK 32768
#define D_IN  256
#define H_LAT 8192
#define TOPK  32
#define MT    64          // rows per block
#define NT    128         // h-cols per chunk
#define NCH   (H_LAT / NT)
#define CAP   144         // candidate pool per row (thr=2.3sigma -> lambda~90)
#define DELTA 0.016f      // exact-rescore window; ~8 sigma of bf16-GEMM+pack err

typedef __attribute__((ext_vector_type(4))) float f32x4;
typedef __attribute__((ext_vector_type(8))) short bf16x8;

__device__ __forceinline__ unsigned short f2bf(float f) {   // RNE fp32->bf16
    unsigned u = __float_as_uint(f);
    return (unsigned short)((u + 0x7fffu + ((u >> 16) & 1u)) >> 16);
}
__device__ __forceinline__ float bf2f(unsigned short u) {
    return __uint_as_float((unsigned)u << 16);
}

// Kernel A: 512 blocks (2 blocks/CU). Block = one 16-col tile; the 4 waves
// split the 8 c8-fragments (2 each). Coalesced swizzled W_enc->bf16 (+sumW^2);
// Wd->bf16 linear copy grid-strided over all 512 blocks. (R13, unchanged.)
__global__ __launch_bounds__(256)
void conv_kernel(const float* __restrict__ W, unsigned short* __restrict__ Wbf,
                 float* __restrict__ s2w, const float* __restrict__ Wd,
                 unsigned short* __restrict__ Wdbf) {
    const int tid  = threadIdx.x;
    const int wave = tid >> 6, lane = tid & 63;
    const int l15 = lane & 15, quad = lane >> 4;
    const int ct16 = blockIdx.x;                        // 512 tiles

    float acc = 0.0f;
    {
        const float* src = W + (size_t)(ct16 * 16 + l15) * D_IN + quad * 8;
        unsigned short* dst = Wbf + (size_t)ct16 * 4096 + lane * 8;
#pragma unroll
        for (int cc = 0; cc < 2; ++cc) {
            const int c8 = wave * 2 + cc;
            const float4 v0 = *(const float4*)(src + c8 * 32);
            const float4 v1 = *(const float4*)(src + c8 * 32 + 4);
            acc += v0.x * v0.x + v0.y * v0.y + v0.z * v0.z + v0.w * v0.w +
                   v1.x * v1.x + v1.y * v1.y + v1.z * v1.z + v1.w * v1.w;
            ushort4 p0, p1;
            p0.x = f2bf(v0.x); p0.y = f2bf(v0.y); p0.z = f2bf(v0.z); p0.w = f2bf(v0.w);
            p1.x = f2bf(v1.x); p1.y = f2bf(v1.y); p1.z = f2bf(v1.z); p1.w = f2bf(v1.w);
            *(ushort4*)(dst + c8 * 512)     = p0;       // coalesced
            *(ushort4*)(dst + c8 * 512 + 4) = p1;
        }
    }
    {
        const int total4 = (H_LAT * D_IN) / 4;
        for (int i = blockIdx.x * 256 + tid; i < total4; i += 512 * 256) {
            const float4 d = ((const float4*)Wd)[i];
            ushort4 od;
            od.x = f2bf(d.x); od.y = f2bf(d.y); od.z = f2bf(d.z); od.w = f2bf(d.w);
            ((ushort4*)Wdbf)[i] = od;
        }
    }
#pragma unroll
    for (int off = 32; off > 0; off >>= 1) acc += __shfl_down(acc, off, 64);
    if (lane == 0) atomicAdd(s2w, acc);
}

// One pipeline step: prefetch next c8's B (global) and A (LDS) fragments while
// the 8 MFMAs consume the previous step's registers. (R14, unchanged.)
#define GSTEP(CW0, CW1, NW0, NW1, CA, NA, NBASE, NC8, NAC8)                    \
    {                                                                          \
        NW0 = *(const bf16x8*)((NBASE) + (NC8) * 512);                         \
        NW1 = *(const bf16x8*)((NBASE) + 32768 + (NC8) * 512);                 \
        NA[0] = *(const bf16x8*)(ap + (0 * 8 + (NAC8)) * 512);                 \
        NA[1] = *(const bf16x8*)(ap + (1 * 8 + (NAC8)) * 512);                 \
        NA[2] = *(const bf16x8*)(ap + (2 * 8 + (NAC8)) * 512);                 \
        NA[3] = *(const bf16x8*)(ap + (3 * 8 + (NAC8)) * 512);                 \
        acc0[0] = __builtin_amdgcn_mfma_f32_16x16x32_bf16(CA[0], CW0, acc0[0], 0, 0, 0); \
        acc0[1] = __builtin_amdgcn_mfma_f32_16x16x32_bf16(CA[1], CW0, acc0[1], 0, 0, 0); \
        acc0[2] = __builtin_amdgcn_mfma_f32_16x16x32_bf16(CA[2], CW0, acc0[2], 0, 0, 0); \
        acc0[3] = __builtin_amdgcn_mfma_f32_16x16x32_bf16(CA[3], CW0, acc0[3], 0, 0, 0); \
        acc1[0] = __builtin_amdgcn_mfma_f32_16x16x32_bf16(CA[0], CW1, acc1[0], 0, 0, 0); \
        acc1[1] = __builtin_amdgcn_mfma_f32_16x16x32_bf16(CA[1], CW1, acc1[1], 0, 0, 0); \
        acc1[2] = __builtin_amdgcn_mfma_f32_16x16x32_bf16(CA[2], CW1, acc1[2], 0, 0, 0); \
        acc1[3] = __builtin_amdgcn_mfma_f32_16x16x32_bf16(CA[3], CW1, acc1[3], 0, 0, 0); \
    }

// Kernel B: R14 GEMM phase (A+B ping-pong) + 2-ROW-ILP tail: each tail
// iteration processes TWO rows, interleaving two independent latency chains
// (rank shuffles, rescore fmafs, decoder gathers) -> ~2x ILP on the
// latency-bound tail that now dominates (~255us of 436).
__global__ __launch_bounds__(512, 4)
void sae_main(const float* __restrict__ x, const float* __restrict__ W_enc,
              const float* __restrict__ b_enc, const float* __restrict__ b_dec,
              float* __restrict__ out,
              const unsigned short* __restrict__ Wbf, const float* __restrict__ s2w,
              const unsigned short* __restrict__ Wdbf) {
    // smem: [0, 32768)     A_frag[32][512] ushort (UNION tail ext scratch 6KB)
    //       [32768, 69632) pool[64][144]
    __shared__ __align__(16) char smem[32768 + MT * CAP * 4];
    __shared__ int   cnt[MT];
    __shared__ float thr[MT];

    unsigned short* A = (unsigned short*)smem;
    auto pool = reinterpret_cast<unsigned (*)[CAP]>(smem + 32768);
    unsigned short* ext_i = (unsigned short*)smem;          // [8 waves][128] (2 KB)
    float*          ext_v = (float*)(smem + 2048);          // [8 waves][128] (4 KB)

    const int tid  = threadIdx.x;
    const int row0 = blockIdx.x * MT;
    const int wave = tid >> 6, lane = tid & 63;
    const int l15 = lane & 15, quad = lane >> 4;

    if (tid < MT) { cnt[tid] = 0; thr[tid] = 0.0f; }
    __syncthreads();

    // ---- Phase 0: stage (x - b_dec) -> bf16 LDS in FRAGMENT order ----
    {
        const int r = tid >> 3, q = tid & 7;                // 8 threads/row, 32 k each
        const float* xr = x + (size_t)(row0 + r) * D_IN + q * 32;
        const float* bd = b_dec + q * 32;
        unsigned short* dst = A + ((r >> 4) * 8 + q) * 512 + (r & 15) * 8;
        float s2 = 0.0f;
#pragma unroll
        for (int j = 0; j < 4; ++j) {                       // j = quad-of-k
            const float4 a = ((const float4*)xr)[2 * j];
            const float4 b = ((const float4*)xr)[2 * j + 1];
            const float4 da = ((const float4*)bd)[2 * j];
            const float4 db = ((const float4*)bd)[2 * j + 1];
            float v[8] = {a.x - da.x, a.y - da.y, a.z - da.z, a.w - da.w,
                          b.x - db.x, b.y - db.y, b.z - db.z, b.w - db.w};
            ushort4 p0, p1;
            p0.x = f2bf(v[0]); p0.y = f2bf(v[1]); p0.z = f2bf(v[2]); p0.w = f2bf(v[3]);
            p1.x = f2bf(v[4]); p1.y = f2bf(v[5]); p1.z = f2bf(v[6]); p1.w = f2bf(v[7]);
#pragma unroll
            for (int e = 0; e < 8; ++e) s2 += v[e] * v[e];
            *(ushort4*)(dst + j * 128)     = p0;
            *(ushort4*)(dst + j * 128 + 4) = p1;
        }
        atomicAdd(&thr[r], s2);
    }
    __syncthreads();
    if (tid < MT) {
        const float s2wm = s2w[0] * (1.0f / ((float)H_LAT * (float)D_IN));
        thr[tid] = 2.3f * sqrtf(s2wm * thr[tid]);
    }
    __syncthreads();

    float thrv[4][4];
#pragma unroll
    for (int mt = 0; mt < 4; ++mt)
#pragma unroll
        for (int qi = 0; qi < 4; ++qi) thrv[mt][qi] = thr[mt * 16 + quad * 4 + qi];

    // ---- Phase 1: MFMA K-loop, 2-chunk groups, A+B ping-pong prefetch ----
    const unsigned short* bp = Wbf + (size_t)(wave * 8) * 512 + lane * 8;
    const unsigned short* ap = A + lane * 8;                // conflict-free A base
    const float* bep = b_enc + wave * 16 + l15;
    int col0 = wave * 16 + l15;

    int pos[4][4];
    auto collect = [&](const f32x4 (&ac)[4], int cbase) {
        const unsigned colk = (unsigned)(8191 - cbase);
#pragma unroll
        for (int mt = 0; mt < 4; ++mt)
#pragma unroll
            for (int qi = 0; qi < 4; ++qi) {
                pos[mt][qi] = -1;
                if (ac[mt][qi] > thrv[mt][qi])
                    pos[mt][qi] = atomicAdd(&cnt[mt * 16 + quad * 4 + qi], 1);
            }
#pragma unroll
        for (int mt = 0; mt < 4; ++mt)
#pragma unroll
            for (int qi = 0; qi < 4; ++qi) {
                if ((unsigned)pos[mt][qi] < CAP)
                    pool[mt * 16 + quad * 4 + qi][pos[mt][qi]] =
                        ((unsigned)f2bf(ac[mt][qi]) << 13) | colk;
            }
    };

    bf16x8 wa0, wa1, wb0, wb1;
    bf16x8 aA[4], aB[4];
    wa0 = *(const bf16x8*)(bp);                             // preload group 0, c8=0
    wa1 = *(const bf16x8*)(bp + 32768);
    aA[0] = *(const bf16x8*)(ap + 0 * 8 * 512);
    aA[1] = *(const bf16x8*)(ap + 1 * 8 * 512);
    aA[2] = *(const bf16x8*)(ap + 2 * 8 * 512);
    aA[3] = *(const bf16x8*)(ap + 3 * 8 * 512);

    for (int g = 0; g < NCH; g += 2) {
        const float bv0 = bep[0], bv1 = bep[NT];

        f32x4 acc0[4], acc1[4];
#pragma unroll
        for (int mt = 0; mt < 4; ++mt) {
            acc0[mt] = {bv0, bv0, bv0, bv0};                // C-in = bias
            acc1[mt] = {bv1, bv1, bv1, bv1};
        }

        GSTEP(wa0, wa1, wb0, wb1, aA, aB, bp, 1, 1);
        GSTEP(wb0, wb1, wa0, wa1, aB, aA, bp, 2, 2);
        GSTEP(wa0, wa1, wb0, wb1, aA, aB, bp, 3, 3);
        GSTEP(wb0, wb1, wa0, wa1, aB, aA, bp, 4, 4);
        GSTEP(wa0, wa1, wb0, wb1, aA, aB, bp, 5, 5);
        GSTEP(wb0, wb1, wa0, wa1, aB, aA, bp, 6, 6);
        GSTEP(wa0, wa1, wb0, wb1, aA, aB, bp, 7, 7);
        GSTEP(wb0, wb1, wa0, wa1, aB, aA, bp + 65536, 0, 0);  // prefetch next group
        // (final group prefetches 16B past Wbf -> lands in Wdbf region: safe, unused)

        collect(acc0, col0);
        collect(acc1, col0 + NT);

        bp  += 65536;                                       // 2 chunks (8 ct16 each)
        bep += 2 * NT;
        col0 += 2 * NT;
    }
    __syncthreads();    // pools complete; A dead -> ext scratch overlays it.
                        // NO barriers below: each wave fully owns its 8 rows.

    unsigned short* ei0 = ext_i + wave * 128;               // this wave's scratch
    unsigned short* ei1 = ei0 + 64;
    float*          ev0 = ext_v + wave * 128;
    float*          ev1 = ev0 + 64;

    for (int rr = 0; rr < 8; rr += 2) {                     // TWO rows per iter
        const int r0 = wave * 8 + rr, r1 = r0 + 1;
        const int n0 = min(cnt[r0], CAP), n1 = min(cnt[r1], CAP);

        // ---- rank-count on packed keys -> top-64 per row, 2 rows in flight ----
        unsigned pA[3], pB[3]; int rkA[3], rkB[3];
        const int S0 = (n0 <= 128) ? 2 : 3;                 // wave-uniform
        const int S1 = (n1 <= 128) ? 2 : 3;
#pragma unroll
        for (int e = 0; e < 3; ++e) {
            const int c = e * 64 + lane;
            pA[e] = (c < n0) ? pool[r0][c] : (unsigned)(c + 1);  // unique tiny sentinels
            pB[e] = (c < n1) ? pool[r1][c] : (unsigned)(c + 1);
            rkA[e] = 0; rkB[e] = 0;
        }
        if (S0 == 2 && S1 == 2) {                           // common path (lambda~90)
            for (int s = 0; s < 64; ++s) {
                const int src = (lane + s) & 63;
                const unsigned qA0 = (unsigned)__shfl((int)pA[0], src, 64);
                const unsigned qA1 = (unsigned)__shfl((int)pA[1], src, 64);
                const unsigned qB0 = (unsigned)__shfl((int)pB[0], src, 64);
                const unsigned qB1 = (unsigned)__shfl((int)pB[1], src, 64);
                rkA[0] += (qA0 > pA[0]) + (qA1 > pA[0]);
                rkA[1] += (qA0 > pA[1]) + (qA1 > pA[1]);
                rkB[0] += (qB0 > pB[0]) + (qB1 > pB[0]);
                rkB[1] += (qB0 > pB[1]) + (qB1 > pB[1]);
            }
        } else {
            for (int s = 0; s < 64; ++s) {
                const int src = (lane + s) & 63;
#pragma unroll
                for (int e = 0; e < 3; ++e) {
                    const unsigned qA = (unsigned)__shfl((int)pA[e], src, 64);
                    const unsigned qB = (unsigned)__shfl((int)pB[e], src, 64);
                    if (e < S0) {                           // only elements in row0's set
                        rkA[0] += (qA > pA[0]); rkA[1] += (qA > pA[1]); rkA[2] += (qA > pA[2]);
                    }
                    if (e < S1) {                           // only elements in row1's set
                        rkB[0] += (qB > pB[0]); rkB[1] += (qB > pB[1]); rkB[2] += (qB > pB[2]);
                    }
                }
            }
        }
#pragma unroll
        for (int e = 0; e < 3; ++e) {
            if (e < S0 && rkA[e] < 64) {
                if (pA[e] >= 8192u) {                       // real entry
                    ei0[rkA[e]] = (unsigned short)(8191 - (pA[e] & 0x1fffu));
                    ev0[rkA[e]] = __uint_as_float((pA[e] >> 13) << 16);
                } else {                                    // filler: unique sentinel
                    ei0[rkA[e]] = (unsigned short)(0x2000 + rkA[e]);
                    ev0[rkA[e]] = 0.0f;
                }
            }
            if (e < S1 && rkB[e] < 64) {
                if (pB[e] >= 8192u) {
                    ei1[rkB[e]] = (unsigned short)(8191 - (pB[e] & 0x1fffu));
                    ev1[rkB[e]] = __uint_as_float((pB[e] >> 13) << 16);
                } else {
                    ei1[rkB[e]] = (unsigned short)(0x2000 + rkB[e]);
                    ev1[rkB[e]] = 0.0f;
                }
            }
        }
        // all 128 slots written by this wave; same-wave LDS ops are ordered

        // ---- exact serial-fmaf rescore, two independent chains (j = lane) ----
        const float v32_0 = ev0[TOPK - 1], v32_1 = ev1[TOPK - 1];
        const float vaA = ev0[lane];  const int hA = ei0[lane];
        const float vaB = ev1[lane];  const int hB = ei1[lane];
        float vA = vaA, vB = vaB;
        const bool doA = (hA < H_LAT && fabsf(vaA - v32_0) <= DELTA);
        const bool doB = (hB < H_LAT && fabsf(vaB - v32_1) <= DELTA);
        if (doA || doB) {
            const float* xr0 = x + (size_t)(row0 + r0) * D_IN;
            const float* xr1 = x + (size_t)(row0 + r1) * D_IN;
            const float* wA = W_enc + (size_t)(doA ? hA : 0) * D_IN;
            const float* wB = W_enc + (size_t)(doB ? hB : 0) * D_IN;
            float sA = 0.0f, sB = 0.0f;
#pragma unroll 16
            for (int kk = 0; kk < D_IN / 4; ++kk) {         // serial fmaf == np oracle
                const float4 dv  = ((const float4*)b_dec)[kk];
                const float4 xv0 = ((const float4*)xr0)[kk];
                const float4 wv0 = ((const float4*)wA)[kk];
                const float4 xv1 = ((const float4*)xr1)[kk];
                const float4 wv1 = ((const float4*)wB)[kk];
                sA = fmaf(xv0.x - dv.x, wv0.x, sA);
                sA = fmaf(xv0.y - dv.y, wv0.y, sA);
                sA = fmaf(xv0.z - dv.z, wv0.z, sA);
                sA = fmaf(xv0.w - dv.w, wv0.w, sA);
                sB = fmaf(xv1.x - dv.x, wv1.x, sB);
                sB = fmaf(xv1.y - dv.y, wv1.y, sB);
                sB = fmaf(xv1.z - dv.z, wv1.z, sB);
                sB = fmaf(xv1.w - dv.w, wv1.w, sB);
            }
            if (doA) vA = fmaxf(sA + b_enc[hA], 0.0f);
            if (doB) vB = fmaxf(sB + b_enc[hB], 0.0f);
        }

        // ---- final rank -> top-32 per row, 2 rows in flight ----
        int rank0 = 0, rank1 = 0;
        for (int s = 0; s < 64; ++s) {
            const int src = (lane + s) & 63;
            const float wv0 = __shfl(vA, src, 64);
            const int   wh0 = __shfl(hA, src, 64);
            const float wv1 = __shfl(vB, src, 64);
            const int   wh1 = __shfl(hB, src, 64);
            rank0 += (wv0 > vA) || (wv0 == vA && wh0 < hA); // val desc, idx asc; unique
            rank1 += (wv1 > vB) || (wv1 == vB && wh1 < hB);
        }
        if (rank0 < TOPK) { ev0[rank0] = vA; ei0[rank0] = (unsigned short)hA; }
        if (rank1 < TOPK) { ev1[rank1] = vB; ei1[rank1] = (unsigned short)hB; }

        // ---- bf16 decoder, two independent gather streams ----
        const float4 bd4 = *(const float4*)&b_dec[lane * 4];
        float4 o0 = bd4, o1 = bd4;                          // wave-in-order: writes visible
#pragma unroll 8
        for (int k = 0; k < TOPK; ++k) {
            const float vv0 = ev0[k]; const int hh0 = ei0[k];   // LDS broadcast
            const float vv1 = ev1[k]; const int hh1 = ei1[k];
            if (hh0 < H_LAT) {                              // wave-uniform (guards sentinel)
                const ushort4 w = *(const ushort4*)&Wdbf[(size_t)hh0 * D_IN + lane * 4];
                o0.x = fmaf(vv0, bf2f(w.x), o0.x); o0.y = fmaf(vv0, bf2f(w.y), o0.y);
                o0.z = fmaf(vv0, bf2f(w.z), o0.z); o0.w = fmaf(vv0, bf2f(w.w), o0.w);
            }
            if (hh1 < H_LAT) {
                const ushort4 w = *(const ushort4*)&Wdbf[(size_t)hh1 * D_IN + lane * 4];
                o1.x = fmaf(vv1, bf2f(w.x), o1.x); o1.y = fmaf(vv1, bf2f(w.y), o1.y);
                o1.z = fmaf(vv1, bf2f(w.z), o1.z); o1.w = fmaf(vv1, bf2f(w.w), o1.w);
            }
        }
        *(float4*)&out[(size_t)(row0 + r0) * D_IN + lane * 4] = o0;
        *(float4*)&out[(size_t)(row0 + r1) * D_IN + lane * 4] = o1;
    }
}

extern "C" void kernel_launch(void* const* d_in, const int* in_sizes, int n_in,
                              void* d_out, int out_size, void* d_ws, size_t ws_size,
                              hipStream_t stream) {
    const float* x     = (const float*)d_in[0];
    const float* W_enc = (const float*)d_in[1];
    const float* b_enc = (const float*)d_in[2];
    const float* W_dec = (const float*)d_in[3];
    const float* b_dec = (const float*)d_in[4];
    float* out = (float*)d_out;

    const size_t wel = (size_t)H_LAT * D_IN;                    // 2M elements
    float* s2w = (float*)d_ws;                                  // 1 float @ offset 0
    unsigned short* Wbf  = (unsigned short*)((char*)d_ws + 256); // 4 MB bf16 W_enc (swizzled)
    unsigned short* Wdbf = Wbf + wel;                            // 4 MB bf16 W_dec (linear)

    hipMemsetAsync(d_ws, 0, 256, stream);                       // zero s2w (ws is poisoned)
    conv_kernel<<<dim3(512), dim3(256), 0, stream>>>(W_enc, Wbf, s2w, W_dec, Wdbf);
    sae_main<<<dim3(B_TOK / MT), dim3(512), 0, stream>>>(x, W_enc, b_enc, b_dec,
                                                         out, Wbf, s2w, Wdbf);
}